// Round 8
// baseline (234.699 us; speedup 1.0000x reference)
//
#include <hip/hip_runtime.h>
#include <hip/hip_bf16.h>

#define PI_F 3.14159265358979323846f

typedef __bf16 bf16x8 __attribute__((ext_vector_type(8)));
typedef float f32x4 __attribute__((ext_vector_type(4)));

// ---------------------------------------------------------------------------
// Kernel 1: forward FFT2 of real 32x32 slices + fused group-stat atomics.
// Rotation-based DFT (phasor recurrence), conjugate symmetry; unchanged r7.
// ---------------------------------------------------------------------------
__global__ __launch_bounds__(256) void k_fft2(const float* __restrict__ x,
                                              float* __restrict__ xr,
                                              float* __restrict__ stats_raw) {
  const int slice = blockIdx.x;  // b*256 + c
  const float* xs = x + (size_t)slice * 1024;
  __shared__ float sx[1056];              // [32][33]
  __shared__ float yre[1056], yim[1056];  // [32][33]
  const int tid = threadIdx.x;
  {
    const float4 v = ((const float4*)xs)[tid];
    const int row = tid >> 3, col = (tid & 7) * 4;
    float* p = &sx[row * 33 + col];
    p[0] = v.x; p[1] = v.y; p[2] = v.z; p[3] = v.w;
  }
  __syncthreads();
  {
    const int i = tid >> 3, kb = tid & 7;
    float stc, sts;
    sincosf(-2.0f * PI_F * (float)kb / 32.0f, &sts, &stc);
    float wr = 1.f, wi = 0.f;
    float zr0 = 0.f, zi0 = 0.f, zr1 = 0.f, zi1 = 0.f, z16 = 0.f;
    const float* rowp = &sx[i * 33];
    for (int j = 0; j < 32; j += 4) {
#pragma unroll
      for (int c = 0; c < 4; ++c) {
        const float a = rowp[j + c];
        const float tr = a * wr, ti = a * wi;
        zr0 += tr; zi0 += ti;
        if (c == 0)      { zr1 += tr; zi1 += ti; }
        else if (c == 1) { zr1 += ti; zi1 -= tr; }
        else if (c == 2) { zr1 -= tr; zi1 -= ti; }
        else             { zr1 -= ti; zi1 += tr; }
        z16 += (c & 1) ? -a : a;
        const float nwr = wr * stc - wi * sts;
        wi = wr * sts + wi * stc;
        wr = nwr;
      }
    }
    float* yr_ = &yre[i * 33];
    float* yi_ = &yim[i * 33];
    yr_[kb] = zr0; yi_[kb] = zi0;
    if (kb >= 1) { yr_[32 - kb] = zr0; yi_[32 - kb] = -zi0; }
    yr_[kb + 8] = zr1; yi_[kb + 8] = zi1;
    yr_[24 - kb] = zr1; yi_[24 - kb] = -zi1;
    if (kb == 0) { yr_[16] = z16; yi_[16] = 0.f; }
  }
  __syncthreads();
  float* op = xr + (size_t)slice * 2048;
  float s1 = 0.f, s2 = 0.f;
  {
    const int k2 = tid & 31, k1b = tid >> 5;
    float stc, sts;
    sincosf(-2.0f * PI_F * (float)k1b / 32.0f, &sts, &stc);
    float wr = 1.f, wi = 0.f;
    float zr0 = 0.f, zi0 = 0.f, zr1 = 0.f, zi1 = 0.f, z16r = 0.f, z16i = 0.f;
    for (int i = 0; i < 32; i += 4) {
#pragma unroll
      for (int c = 0; c < 4; ++c) {
        const float ar = yre[(i + c) * 33 + k2];
        const float ai = yim[(i + c) * 33 + k2];
        const float tr = ar * wr - ai * wi;
        const float ti = ar * wi + ai * wr;
        zr0 += tr; zi0 += ti;
        if (c == 0)      { zr1 += tr; zi1 += ti; }
        else if (c == 1) { zr1 += ti; zi1 -= tr; }
        else if (c == 2) { zr1 -= tr; zi1 -= ti; }
        else             { zr1 -= ti; zi1 += tr; }
        if (c & 1) { z16r -= ar; z16i -= ai; }
        else       { z16r += ar; z16i += ai; }
        const float nwr = wr * stc - wi * sts;
        wi = wr * sts + wi * stc;
        wr = nwr;
      }
    }
    if (k1b == 0) {
      op[2 * k2] = zr0; op[2 * k2 + 1] = zi0;
      s1 += zr0 + zi0; s2 += zr0 * zr0 + zi0 * zi0;
    } else {
      const int e0 = k1b * 32 + k2;
      op[2 * e0] = zr0; op[2 * e0 + 1] = zi0;
      const int em = (32 - k1b) * 32 + ((32 - k2) & 31);
      op[2 * em] = zr0; op[2 * em + 1] = -zi0;
      s1 += 2.0f * zr0; s2 += 2.0f * (zr0 * zr0 + zi0 * zi0);
    }
    {
      const int k1 = k1b + 8;
      const int e0 = k1 * 32 + k2;
      op[2 * e0] = zr1; op[2 * e0 + 1] = zi1;
      const int em = (32 - k1) * 32 + ((32 - k2) & 31);
      op[2 * em] = zr1; op[2 * em + 1] = -zi1;
      s1 += 2.0f * zr1; s2 += 2.0f * (zr1 * zr1 + zi1 * zi1);
    }
    if (k1b == 0) {
      const int e0 = 16 * 32 + k2;
      op[2 * e0] = z16r; op[2 * e0 + 1] = z16i;
      s1 += z16r + z16i; s2 += z16r * z16r + z16i * z16i;
    }
  }
#pragma unroll
  for (int off = 1; off <= 32; off <<= 1) {
    s1 += __shfl_xor(s1, off);
    s2 += __shfl_xor(s2, off);
  }
  if ((tid & 63) == 0) {
    const int bg = (slice >> 8) * 32 + ((slice & 255) >> 3);
    atomicAdd(&stats_raw[bg * 2], s1);
    atomicAdd(&stats_raw[bg * 2 + 1], s2);
  }
}

// ---------------------------------------------------------------------------
// Kernel 2: GroupNorm apply (from raw sums) + transpose to bf16 X^T [b][n][c].
// ---------------------------------------------------------------------------
__global__ __launch_bounds__(256) void k_gntrans(const float* __restrict__ xr,
                                                 const float* __restrict__ stats_raw,
                                                 const float* __restrict__ w,
                                                 const float* __restrict__ bias,
                                                 __bf16* __restrict__ xt) {
  const int n0 = blockIdx.x * 64;
  const int c0 = blockIdx.y * 64;
  const int b = blockIdx.z;
  __shared__ __bf16 Lt[64][72];
  const int tid = threadIdx.x;
  for (int i = tid; i < 1024; i += 256) {
    const int cl = i >> 4, c = c0 + cl, nl = (i & 15) * 4;
    const float S = stats_raw[(b * 32 + (c >> 3)) * 2];
    const float S2 = stats_raw[(b * 32 + (c >> 3)) * 2 + 1];
    const float mean = S * (1.0f / 16384.0f);
    const float var = S2 * (1.0f / 16384.0f) - mean * mean;
    const float rstd = rsqrtf(var + 1e-5f);
    const float sc = rstd * w[c];
    const float sh = bias[c] - mean * sc;
    const float4 v = *(const float4*)(xr + ((size_t)b * 256 + c) * 2048 + n0 + nl);
    Lt[nl][cl] = (__bf16)(v.x * sc + sh);
    Lt[nl + 1][cl] = (__bf16)(v.y * sc + sh);
    Lt[nl + 2][cl] = (__bf16)(v.z * sc + sh);
    Lt[nl + 3][cl] = (__bf16)(v.w * sc + sh);
  }
  __syncthreads();
  __bf16* dst = xt + (size_t)b * 524288 + (size_t)n0 * 256 + c0;
  for (int i = tid; i < 512; i += 256) {
    const int nl = i >> 3, cch = (i & 7) * 8;
    *(uint4*)(dst + (size_t)nl * 256 + cch) = *(const uint4*)&Lt[nl][cch];
  }
}

// ---------------------------------------------------------------------------
// Kernel 3: QKV GEMM (bf16 MFMA), fp32 weights cast in A-staging, register
// prefetch pipeline, fused prep epilogue; unchanged r7.
// ---------------------------------------------------------------------------
__global__ __launch_bounds__(256) void k_gemm_qkv(const float* __restrict__ W,
                                                  const __bf16* __restrict__ X,
                                                  const float* __restrict__ bias,
                                                  __bf16* __restrict__ Qt,
                                                  __bf16* __restrict__ Kt,
                                                  __bf16* __restrict__ Vt) {
  const int n0 = blockIdx.x * 128;
  const int seg = blockIdx.y;          // 0..11: head = seg/3, role = seg%3
  const int b = blockIdx.z;
  const int bo = seg * 64;
  const __bf16* Xb = X + (size_t)b * 524288;

  __shared__ __align__(16) char smem[18432];
  __bf16 (*As)[40] = (__bf16(*)[40])smem;           // [64][40]
  __bf16 (*Bs)[40] = (__bf16(*)[40])(smem + 5120);  // [128][40]
  __bf16 (*Ot)[72] = (__bf16(*)[72])smem;           // Q/K epilogue alias
  __bf16 (*Ot2)[136] = (__bf16(*)[136])smem;        // V epilogue alias

  const int tid = threadIdx.x, lane = tid & 63, wv = tid >> 6;
  const int quad = lane >> 4, q16 = lane & 15, wn = wv * 32;

  const int rowA = tid >> 2, chA = (tid & 3) * 8;
  const int browB0 = tid >> 2, bchB = (tid & 3) * 8;
  const float* wA = W + (size_t)(bo + rowA) * 256 + chA;

  float4 aP0 = *(const float4*)(wA);
  float4 aP1 = *(const float4*)(wA + 4);
  uint4 bP0 = *(const uint4*)(Xb + (size_t)(n0 + browB0) * 256 + bchB);
  uint4 bP1 = *(const uint4*)(Xb + (size_t)(n0 + browB0 + 64) * 256 + bchB);

  f32x4 acc[4][2] = {};
  for (int k0 = 0; k0 < 256; k0 += 32) {
    {
      union { uint4 u; __bf16 h[8]; } pa;
      pa.h[0] = (__bf16)aP0.x; pa.h[1] = (__bf16)aP0.y;
      pa.h[2] = (__bf16)aP0.z; pa.h[3] = (__bf16)aP0.w;
      pa.h[4] = (__bf16)aP1.x; pa.h[5] = (__bf16)aP1.y;
      pa.h[6] = (__bf16)aP1.z; pa.h[7] = (__bf16)aP1.w;
      *(uint4*)&As[rowA][chA] = pa.u;
      *(uint4*)&Bs[browB0][bchB] = bP0;
      *(uint4*)&Bs[browB0 + 64][bchB] = bP1;
    }
    __syncthreads();
    if (k0 + 32 < 256) {
      const int kn = k0 + 32;
      aP0 = *(const float4*)(wA + kn);
      aP1 = *(const float4*)(wA + kn + 4);
      bP0 = *(const uint4*)(Xb + (size_t)(n0 + browB0) * 256 + kn + bchB);
      bP1 = *(const uint4*)(Xb + (size_t)(n0 + browB0 + 64) * 256 + kn + bchB);
    }
    bf16x8 af[4], bfr[2];
#pragma unroll
    for (int mt = 0; mt < 4; ++mt) af[mt] = *(const bf16x8*)&As[mt * 16 + q16][quad * 8];
#pragma unroll
    for (int jn = 0; jn < 2; ++jn) bfr[jn] = *(const bf16x8*)&Bs[wn + jn * 16 + q16][quad * 8];
#pragma unroll
    for (int mt = 0; mt < 4; ++mt)
#pragma unroll
      for (int jn = 0; jn < 2; ++jn)
        acc[mt][jn] = __builtin_amdgcn_mfma_f32_16x16x32_bf16(af[mt], bfr[jn], acc[mt][jn], 0, 0, 0);
    __syncthreads();
  }

  const int hd = seg / 3, role = seg % 3;
  const int bh = b * 4 + hd;
  if (role == 2) {
#pragma unroll
    for (int mt = 0; mt < 4; ++mt)
#pragma unroll
      for (int r = 0; r < 4; ++r) {
        const int c = mt * 16 + quad * 4 + r;
        const float bv = bias[bo + c];
#pragma unroll
        for (int jn = 0; jn < 2; ++jn)
          Ot2[c][wn + jn * 16 + q16] = (__bf16)(acc[mt][jn][r] + bv);
      }
    __syncthreads();
    __bf16* dst = Vt + (size_t)bh * 131072;  // [c][s]
    for (int i = tid; i < 1024; i += 256) {
      const int c = i >> 4, sg = (i & 15) * 8;
      *(uint4*)(dst + (size_t)c * 2048 + n0 + sg) = *(const uint4*)&Ot2[c][sg];
    }
  } else {
    __bf16* dst = (role == 0 ? Qt : Kt) + (size_t)bh * 131072;  // [n][c]
#pragma unroll
    for (int mt = 0; mt < 4; ++mt)
#pragma unroll
      for (int r = 0; r < 4; ++r) {
        const int c = mt * 16 + quad * 4 + r;
        const float bv = bias[bo + c];
#pragma unroll
        for (int jn = 0; jn < 2; ++jn)
          Ot[wn + jn * 16 + q16][c] = (__bf16)(acc[mt][jn][r] + bv);
      }
    __syncthreads();
    for (int i = tid; i < 1024; i += 256) {
      const int nl = i >> 3, cch = (i & 7) * 8;
      *(uint4*)(dst + (size_t)(n0 + nl) * 64 + cch) = *(const uint4*)&Ot[nl][cch];
    }
  }
}

// ---------------------------------------------------------------------------
// Kernel 4: MFMA flash attention. S^T form; s-tile 32; s-split x4; register
// prefetch. XOR-swizzled unpadded LDS (16 KB): 16B granule g of row r lives
// at g^(r&7) within a 128B macro-row -> every quarter-wave fragment access
// hits each bank-group with exactly 2 lanes (conflict-free, m136).
// ---------------------------------------------------------------------------
__global__ __launch_bounds__(256) void k_attn_mfma(const __bf16* __restrict__ Qt,
                                                   const __bf16* __restrict__ Kt,
                                                   const __bf16* __restrict__ Vt,
                                                   __bf16* __restrict__ opart,
                                                   float* __restrict__ lpart) {
  const int t0 = blockIdx.x * 128;
  const int part = blockIdx.y;  // 0..3
  const int bh = blockIdx.z;
  const __bf16* kt = Kt + (size_t)bh * 131072;
  const __bf16* vt = Vt + (size_t)bh * 131072;

  // Ks [0,4096): 32 s-rows x 128B.  Vs [4096,8192): 32 macro(c/2) x 128B.
  // Ps [8192,16384): 64 macro(t/2) x 128B.
  __shared__ __align__(16) char smem[16384];

  const int tid = threadIdx.x, lane = tid & 63, wv = tid >> 6;
  const int quad = lane >> 4, q16 = lane & 15;
  const int wband = wv * 32;

  // --- staging pointers (loop-invariant) ---
  const int rK = tid >> 3, gK = tid & 7;
  char* const kw = smem + rK * 128 + ((gK ^ (rK & 7)) * 16);
  const int cV = tid >> 2, gV = tid & 3;
  char* const vw = smem + 4096 + (cV >> 1) * 128 +
                   ((((cV & 1) * 4 + gV) ^ ((cV >> 1) & 7)) * 16);
  const __bf16* const kg = kt + (size_t)rK * 64 + gK * 8;   // + s0*64
  const __bf16* const vg = vt + (size_t)cV * 2048 + gV * 8; // + s0

  // --- fragment read pointers (loop-invariant) ---
  const char* krp[2][2];
#pragma unroll
  for (int j = 0; j < 2; ++j)
#pragma unroll
    for (int kk = 0; kk < 2; ++kk)
      krp[j][kk] = smem + (j * 16 + q16) * 128 + (((kk * 4 + quad) ^ (q16 & 7)) * 16);
  const int a7 = (q16 >> 1) & 7, p1 = q16 & 1;
  const char* vrp[4];
#pragma unroll
  for (int jc = 0; jc < 4; ++jc)
    vrp[jc] = smem + 4096 + (jc * 8 + (q16 >> 1)) * 128 +
              (((p1 * 4 + quad) ^ a7) * 16);
  char* pwp[2][2];
  const char* prp[2];
#pragma unroll
  for (int b = 0; b < 2; ++b) {
    const int mrow = ((wband + b * 16) >> 1) + (q16 >> 1);
    prp[b] = smem + 8192 + mrow * 128 + (((p1 * 4 + quad) ^ a7) * 16);
#pragma unroll
    for (int j = 0; j < 2; ++j)
      pwp[b][j] = smem + 8192 + mrow * 128 +
                  (((p1 * 4 + j * 2 + (quad >> 1)) ^ a7) * 16) + (quad & 1) * 8;
  }

  // Q B-fragments from global
  const __bf16* qbase = Qt + (size_t)bh * 131072;
  bf16x8 bq[2][2];
#pragma unroll
  for (int b = 0; b < 2; ++b) {
    const __bf16* qp = qbase + (size_t)(t0 + wband + b * 16 + q16) * 64 + quad * 8;
    bq[b][0] = *(const bf16x8*)qp;
    bq[b][1] = *(const bf16x8*)(qp + 32);
  }

  f32x4 oacc[2][4] = {};
  float lsum[2] = {0.f, 0.f};

  const int sbase = part * 512, send = sbase + 512;
  uint4 kA = *(const uint4*)(kg + (size_t)sbase * 64);
  uint4 vA = *(const uint4*)(vg + sbase);

  for (int s0 = sbase; s0 < send; s0 += 32) {
    *(uint4*)kw = kA;
    *(uint4*)vw = vA;
    __syncthreads();
    if (s0 + 32 < send) {
      kA = *(const uint4*)(kg + (size_t)(s0 + 32) * 64);
      vA = *(const uint4*)(vg + s0 + 32);
    }

    // S^T: D[m=s][n=t]; K fragments shared across both t-bands
    f32x4 sacc[2][2] = {};
#pragma unroll
    for (int j = 0; j < 2; ++j)
#pragma unroll
      for (int kk = 0; kk < 2; ++kk) {
        const bf16x8 ak = *(const bf16x8*)krp[j][kk];
        sacc[0][j] = __builtin_amdgcn_mfma_f32_16x16x32_bf16(ak, bq[0][kk], sacc[0][j], 0, 0, 0);
        sacc[1][j] = __builtin_amdgcn_mfma_f32_16x16x32_bf16(ak, bq[1][kk], sacc[1][j], 0, 0, 0);
      }

#pragma unroll
    for (int b = 0; b < 2; ++b) {
      float lacc = 0.f;
#pragma unroll
      for (int j = 0; j < 2; ++j) {
        const float p0 = exp2f(fmaf(sacc[b][j][0], 0.18033688f, -23.083120f));
        const float p1v = exp2f(fmaf(sacc[b][j][1], 0.18033688f, -23.083120f));
        const float p2 = exp2f(fmaf(sacc[b][j][2], 0.18033688f, -23.083120f));
        const float p3 = exp2f(fmaf(sacc[b][j][3], 0.18033688f, -23.083120f));
        lacc += (p0 + p1v) + (p2 + p3);
        union { uint2 u; __bf16 h[4]; } pk;
        pk.h[0] = (__bf16)p0; pk.h[1] = (__bf16)p1v;
        pk.h[2] = (__bf16)p2; pk.h[3] = (__bf16)p3;
        *(uint2*)pwp[b][j] = pk.u;
      }
      lsum[b] += lacc;
    }
    // same-wave ds write->read ordering; compiler fence to keep program order
    asm volatile("" ::: "memory");

    bf16x8 bp[2];
    bp[0] = *(const bf16x8*)prp[0];
    bp[1] = *(const bf16x8*)prp[1];
#pragma unroll
    for (int jc = 0; jc < 4; ++jc) {
      const bf16x8 av = *(const bf16x8*)vrp[jc];
      oacc[0][jc] = __builtin_amdgcn_mfma_f32_16x16x32_bf16(av, bp[0], oacc[0][jc], 0, 0, 0);
      oacc[1][jc] = __builtin_amdgcn_mfma_f32_16x16x32_bf16(av, bp[1], oacc[1][jc], 0, 0, 0);
    }
    __syncthreads();
  }

  // partial epilogue: raw o (bf16) + l (fp32)
#pragma unroll
  for (int b = 0; b < 2; ++b) {
    float l = lsum[b];
    l += __shfl_xor(l, 16);
    l += __shfl_xor(l, 32);
    const int t = t0 + wband + b * 16 + q16;
    const size_t row = (size_t)(bh * 4 + part) * 2048 + t;
    if (quad == 0) lpart[row] = l;
    __bf16* opp = opart + row * 64;
#pragma unroll
    for (int jc = 0; jc < 4; ++jc) {
      union { uint2 u; __bf16 h[4]; } pk;
      pk.h[0] = (__bf16)oacc[b][jc][0];
      pk.h[1] = (__bf16)oacc[b][jc][1];
      pk.h[2] = (__bf16)oacc[b][jc][2];
      pk.h[3] = (__bf16)oacc[b][jc][3];
      *(uint2*)(opp + jc * 16 + quad * 4) = pk.u;
    }
  }
}

// ---------------------------------------------------------------------------
// Kernel 5: combine 4-way s-split partials -> at[b][t][256] bf16 (coalesced).
// ---------------------------------------------------------------------------
__global__ __launch_bounds__(256) void k_attn_combine(const __bf16* __restrict__ opart,
                                                      const float* __restrict__ lpart,
                                                      __bf16* __restrict__ at) {
  const int idx = blockIdx.x * 256 + threadIdx.x;  // 0..1048575
  const int cu = idx & 15;
  const int t = (idx >> 4) & 2047;
  const int bh = idx >> 15;
  const size_t r0 = (size_t)(bh * 4) * 2048 + t;
  union { uint2 u; __bf16 h[4]; } a0, a1, a2, a3, o;
  a0.u = *(const uint2*)(opart + r0 * 64 + cu * 4);
  a1.u = *(const uint2*)(opart + (r0 + 2048) * 64 + cu * 4);
  a2.u = *(const uint2*)(opart + (r0 + 4096) * 64 + cu * 4);
  a3.u = *(const uint2*)(opart + (r0 + 6144) * 64 + cu * 4);
  const float inv = 1.0f / (lpart[r0] + lpart[r0 + 2048] +
                            lpart[r0 + 4096] + lpart[r0 + 6144]);
#pragma unroll
  for (int k = 0; k < 4; ++k)
    o.h[k] = (__bf16)((((float)a0.h[k] + (float)a1.h[k]) +
                       ((float)a2.h[k] + (float)a3.h[k])) * inv);
  const int b = bh >> 2, hd = bh & 3;
  *(uint2*)(at + ((size_t)b * 2048 + t) * 256 + hd * 64 + cu * 4) = o.u;
}

// ---------------------------------------------------------------------------
// Kernel 6: proj GEMM (bf16 MFMA), fp32 weights cast in A-staging, clean
// prefetched B-staging from at, fp32 epilogue.
// ---------------------------------------------------------------------------
__global__ __launch_bounds__(256) void k_gemm_proj(const float* __restrict__ W,
                                                   const __bf16* __restrict__ X,
                                                   const float* __restrict__ bias,
                                                   float* __restrict__ C) {
  const int n0 = blockIdx.x * 128;
  const int bo = blockIdx.y * 64;
  const int b = blockIdx.z;
  const __bf16* Xb = X + (size_t)b * 524288;
  float* Cb = C + (size_t)b * 524288;

  __shared__ __align__(16) char smem[15360];
  __bf16 (*As)[40] = (__bf16(*)[40])smem;
  __bf16 (*Bs)[40] = (__bf16(*)[40])(smem + 5120);

  const int tid = threadIdx.x, lane = tid & 63, wv = tid >> 6;
  const int quad = lane >> 4, q16 = lane & 15, wn = wv * 32;

  const int rowA = tid >> 2, chA = (tid & 3) * 8;
  const int browB0 = tid >> 2, bchB = (tid & 3) * 8;
  const float* wA = W + (size_t)(bo + rowA) * 256 + chA;

  float4 aP0 = *(const float4*)(wA);
  float4 aP1 = *(const float4*)(wA + 4);
  uint4 bP0 = *(const uint4*)(Xb + (size_t)(n0 + browB0) * 256 + bchB);
  uint4 bP1 = *(const uint4*)(Xb + (size_t)(n0 + browB0 + 64) * 256 + bchB);

  f32x4 acc[4][2] = {};
  for (int k0 = 0; k0 < 256; k0 += 32) {
    {
      union { uint4 u; __bf16 h[8]; } pa;
      pa.h[0] = (__bf16)aP0.x; pa.h[1] = (__bf16)aP0.y;
      pa.h[2] = (__bf16)aP0.z; pa.h[3] = (__bf16)aP0.w;
      pa.h[4] = (__bf16)aP1.x; pa.h[5] = (__bf16)aP1.y;
      pa.h[6] = (__bf16)aP1.z; pa.h[7] = (__bf16)aP1.w;
      *(uint4*)&As[rowA][chA] = pa.u;
      *(uint4*)&Bs[browB0][bchB] = bP0;
      *(uint4*)&Bs[browB0 + 64][bchB] = bP1;
    }
    __syncthreads();
    if (k0 + 32 < 256) {
      const int kn = k0 + 32;
      aP0 = *(const float4*)(wA + kn);
      aP1 = *(const float4*)(wA + kn + 4);
      bP0 = *(const uint4*)(Xb + (size_t)(n0 + browB0) * 256 + kn + bchB);
      bP1 = *(const uint4*)(Xb + (size_t)(n0 + browB0 + 64) * 256 + kn + bchB);
    }
    bf16x8 af[4], bfr[2];
#pragma unroll
    for (int mt = 0; mt < 4; ++mt) af[mt] = *(const bf16x8*)&As[mt * 16 + q16][quad * 8];
#pragma unroll
    for (int jn = 0; jn < 2; ++jn) bfr[jn] = *(const bf16x8*)&Bs[wn + jn * 16 + q16][quad * 8];
#pragma unroll
    for (int mt = 0; mt < 4; ++mt)
#pragma unroll
      for (int jn = 0; jn < 2; ++jn)
        acc[mt][jn] = __builtin_amdgcn_mfma_f32_16x16x32_bf16(af[mt], bfr[jn], acc[mt][jn], 0, 0, 0);
    __syncthreads();
  }

#pragma unroll
  for (int mt = 0; mt < 4; ++mt)
#pragma unroll
    for (int r = 0; r < 4; ++r) {
      const int o = bo + mt * 16 + quad * 4 + r;
      const float bv = bias[o];
#pragma unroll
      for (int jn = 0; jn < 2; ++jn)
        Cb[(size_t)o * 2048 + n0 + wn + jn * 16 + q16] = acc[mt][jn][r] + bv;
    }
}

// ---------------------------------------------------------------------------
// Kernel 7: inverse FFT2, rotation-based; unchanged r7.
// ---------------------------------------------------------------------------
__global__ __launch_bounds__(256) void k_ifft2(const float* __restrict__ spec,
                                               float* __restrict__ out) {
  const int slice = blockIdx.x;
  const float* sp = spec + (size_t)slice * 2048;
  __shared__ float xre[1056], xim[1056];
  __shared__ float yre[1056], yim[1056];
  const int tid = threadIdx.x;
  for (int i = tid; i < 512; i += 256) {
    const float4 v = ((const float4*)sp)[i];
    const int k1 = i >> 4, k2 = (i & 15) * 2;
    xre[k1 * 33 + k2] = v.x;     xim[k1 * 33 + k2] = v.y;
    xre[k1 * 33 + k2 + 1] = v.z; xim[k1 * 33 + k2 + 1] = v.w;
  }
  __syncthreads();
  {
    const int k1 = tid >> 3, n2b = tid & 7;
    float stc, sts;
    sincosf(2.0f * PI_F * (float)n2b / 32.0f, &sts, &stc);
    float wr = 1.f, wi = 0.f;
    float zr[4] = {0.f, 0.f, 0.f, 0.f}, zi[4] = {0.f, 0.f, 0.f, 0.f};
    const float* xr_ = &xre[k1 * 33];
    const float* xi_ = &xim[k1 * 33];
    for (int k2 = 0; k2 < 32; k2 += 4) {
#pragma unroll
      for (int c = 0; c < 4; ++c) {
        const float ar = xr_[k2 + c], ai = xi_[k2 + c];
        const float tr = ar * wr - ai * wi;
        const float ti = ar * wi + ai * wr;
        zr[0] += tr; zi[0] += ti;
        if (c == 0)      { zr[1] += tr; zi[1] += ti; }
        else if (c == 1) { zr[1] -= ti; zi[1] += tr; }
        else if (c == 2) { zr[1] -= tr; zi[1] -= ti; }
        else             { zr[1] += ti; zi[1] -= tr; }
        if (c & 1) { zr[2] -= tr; zi[2] -= ti; }
        else       { zr[2] += tr; zi[2] += ti; }
        if (c == 0)      { zr[3] += tr; zi[3] += ti; }
        else if (c == 1) { zr[3] += ti; zi[3] -= tr; }
        else if (c == 2) { zr[3] -= tr; zi[3] -= ti; }
        else             { zr[3] -= ti; zi[3] += tr; }
        const float nwr = wr * stc - wi * sts;
        wi = wr * sts + wi * stc;
        wr = nwr;
      }
    }
#pragma unroll
    for (int u = 0; u < 4; ++u) {
      yre[k1 * 33 + n2b + 8 * u] = zr[u];
      yim[k1 * 33 + n2b + 8 * u] = zi[u];
    }
  }
  __syncthreads();
  {
    const int n2 = tid & 31, n1b = tid >> 5;
    float stc, sts;
    sincosf(2.0f * PI_F * (float)n1b / 32.0f, &sts, &stc);
    float wr = 1.f, wi = 0.f;
    float zr[4] = {0.f, 0.f, 0.f, 0.f}, zi[4] = {0.f, 0.f, 0.f, 0.f};
    for (int k1 = 0; k1 < 32; k1 += 4) {
#pragma unroll
      for (int c = 0; c < 4; ++c) {
        const float ar = yre[(k1 + c) * 33 + n2];
        const float ai = yim[(k1 + c) * 33 + n2];
        const float tr = ar * wr - ai * wi;
        const float ti = ar * wi + ai * wr;
        zr[0] += tr; zi[0] += ti;
        if (c == 0)      { zr[1] += tr; zi[1] += ti; }
        else if (c == 1) { zr[1] -= ti; zi[1] += tr; }
        else if (c == 2) { zr[1] -= tr; zi[1] -= ti; }
        else             { zr[1] += ti; zi[1] -= tr; }
        if (c & 1) { zr[2] -= tr; zi[2] -= ti; }
        else       { zr[2] += tr; zi[2] += ti; }
        if (c == 0)      { zr[3] += tr; zi[3] += ti; }
        else if (c == 1) { zr[3] += ti; zi[3] -= tr; }
        else if (c == 2) { zr[3] -= tr; zi[3] -= ti; }
        else             { zr[3] -= ti; zi[3] += tr; }
        const float nwr = wr * stc - wi * sts;
        wi = wr * sts + wi * stc;
        wr = nwr;
      }
    }
    float* op = out + (size_t)slice * 2048;
#pragma unroll
    for (int u = 0; u < 4; ++u) {
      const int n1 = n1b + 8 * u;
      float2 st;
      st.x = zr[u] * (1.0f / 1024.0f);
      st.y = zi[u] * (1.0f / 1024.0f);
      *(float2*)(op + 2 * (n1 * 32 + n2)) = st;
    }
  }
}

// ---------------------------------------------------------------------------
extern "C" void kernel_launch(void* const* d_in, const int* in_sizes, int n_in,
                              void* d_out, int out_size, void* d_ws, size_t ws_size,
                              hipStream_t stream) {
  (void)in_sizes; (void)n_in; (void)out_size; (void)ws_size;
  const float* x      = (const float*)d_in[0];
  const float* gn_w   = (const float*)d_in[1];
  const float* gn_b   = (const float*)d_in[2];
  const float* qkv_w  = (const float*)d_in[3];
  const float* qkv_b  = (const float*)d_in[4];
  const float* proj_w = (const float*)d_in[5];
  const float* proj_b = (const float*)d_in[6];
  float* out = (float*)d_out;

  // ws (~81MB): spec 16MB | Qt/Kt/Vt bf16 8MB each | stats 2KB | xr 16MB |
  //   xt 8MB | (opart 32MB overlaps dead xr+xt) | lpart 1MB | at 8MB
  float* spec  = (float*)d_ws;
  __bf16* Qt   = (__bf16*)(spec + 4194304);
  __bf16* Kt   = Qt + 4194304;
  __bf16* Vt   = Kt + 4194304;
  float* stats = (float*)(Vt + 4194304);
  float* xr    = stats + 512;
  __bf16* xt   = (__bf16*)(xr + 4194304);
  __bf16* opart = (__bf16*)xr;            // clobbers dead xr+xt
  float*  lpart = (float*)(opart + 16777216);
  __bf16* at    = (__bf16*)(lpart + 262144);

  hipMemsetAsync(stats, 0, 512 * sizeof(float), stream);
  k_fft2<<<2048, 256, 0, stream>>>(x, xr, stats);
  k_gntrans<<<dim3(32, 4, 8), 256, 0, stream>>>(xr, stats, gn_w, gn_b, xt);
  k_gemm_qkv<<<dim3(16, 12, 8), 256, 0, stream>>>(qkv_w, xt, qkv_b, Qt, Kt, Vt);
  k_attn_mfma<<<dim3(16, 4, 32), 256, 0, stream>>>(Qt, Kt, Vt, opart, lpart);
  k_attn_combine<<<4096, 256, 0, stream>>>(opart, lpart, at);
  k_gemm_proj<<<dim3(16, 4, 8), 256, 0, stream>>>(proj_w, at, proj_b, spec);
  k_ifft2<<<2048, 256, 0, stream>>>(spec, out);
}